// Round 9
// baseline (539.531 us; speedup 1.0000x reference)
//
#include <hip/hip_runtime.h>
#include <stdint.h>

#define N_NODES 50000
#define N_EDGES 800000
#define IN_CH   512
#define HID_CH  256
#define OUT_CH  128
#define NPAD    50048
#define SLOT    96      // padded CSR slots/node; P(Poisson(16) > 96) ~ 0

#define NB_E   3125     // ceil(800000/256)
#define NB3    782      // 64-row GEMM tiles = partial max strips (50048/64)

// zero "dud" gather rows (memset once): bufH bytes [N_NODES*512, NPAD*512)
#define DUD256 50000    // L0 table: row stride 512B -> byte 25,600,000 (zeroed)
#define DUD128 100000   // L1 table: row stride 256B -> byte 25,600,000 (zeroed)

// k_prep block ranges: bucket scatter + weight split/transpose fused
#define PBKT  NB_E          // 3125 bucket blocks (256 edges each)
#define PW0B  (PBKT + 64)   // W0 split+T: 131072/2048
#define PW1B  (PW0B + 16)   // W1 split+T: 32768/2048
#define PPWB  (PW1B + 8)    // PW split+T: 16384/2048

typedef unsigned short ushort_t;
typedef __attribute__((ext_vector_type(8))) short    short8;  // 8 bf16 (MFMA A/B frag)
typedef __attribute__((ext_vector_type(4))) float    floatx4; // MFMA C/D frag
typedef __attribute__((ext_vector_type(4))) _Float16 half4v;  // 8B gather chunk
typedef __attribute__((ext_vector_type(2))) _Float16 half2v;  // 4B gather chunk

__device__ inline ushort_t f2bf(float x) {                  // fp32 -> bf16 RNE
    union { float f; unsigned u; } v; v.f = x;
    unsigned r = v.u + 0x7fffu + ((v.u >> 16) & 1u);
    return (ushort_t)(r >> 16);
}
__device__ inline float bf2f(ushort_t h) {
    union { unsigned u; float f; } v; v.u = ((unsigned)h) << 16;
    return v.f;
}
__device__ inline void gl_lds16(const void* g, void* l) {   // async global->LDS, 16B/lane
    __builtin_amdgcn_global_load_lds((const __attribute__((address_space(1))) void*)g,
                                     (__attribute__((address_space(3))) void*)l, 16, 0, 0);
}

// LDS bank swizzle: XOR on the 16B-chunk index within each 64B k-row by
// (row>>1)&3.  All producers of split-bf16 GEMM operands store through the
// SAME swizzle so global_load_lds (linear dest) lands already-swizzled tiles.
#define SWZ(r) ((((r) >> 1) & 3) << 3)

// ---------------- fused prep: bucket scatter + weight split+transpose (swizzled) --------
__device__ inline void conv_splitT8(const float* __restrict__ W,
                                    ushort_t* __restrict__ WhT,
                                    ushort_t* __restrict__ WlT,
                                    int K, int N, int base) {
    float4 v0 = *(const float4*)(W + base);
    float4 v1 = *(const float4*)(W + base + 4);
    float vv[8] = {v0.x, v0.y, v0.z, v0.w, v1.x, v1.y, v1.z, v1.w};
    #pragma unroll
    for (int j = 0; j < 8; ++j) {
        int g = base + j;
        int k = g / N, n = g - k * N;
        int ks = k ^ SWZ(n);                       // swizzled storage position
        ushort_t h = f2bf(vv[j]);
        WhT[(size_t)n * K + ks] = h;
        WlT[(size_t)n * K + ks] = f2bf(vv[j] - bf2f(h));
    }
}

__global__ __launch_bounds__(256) void k_prep(const int* __restrict__ esrc,
                                              const int* __restrict__ edst,
                                              const float* __restrict__ W0,
                                              const float* __restrict__ W1,
                                              const float* __restrict__ PW,
                                              int* __restrict__ cnt,
                                              int* __restrict__ slots,
                                              ushort_t* W0hT, ushort_t* W0lT,
                                              ushort_t* W1hT, ushort_t* W1lT,
                                              ushort_t* PWhT, ushort_t* PWlT) {
    int b = blockIdx.x, tid = threadIdx.x;
    if (b < PBKT) {                                // padded-bucket CSR scatter
        int e = b * 256 + tid;
        if (e < N_EDGES) {
            int d = edst[e];
            int c = atomicAdd(&cnt[d], 1);
            slots[(size_t)d * SLOT + c] = esrc[e];
        }
    } else if (b < PW0B) {
        conv_splitT8(W0, W0hT, W0lT, IN_CH, HID_CH, (b - PBKT) * 2048 + tid * 8);
    } else if (b < PW1B) {
        conv_splitT8(W1, W1hT, W1lT, HID_CH, OUT_CH, (b - PW0B) * 2048 + tid * 8);
    } else {
        conv_splitT8(PW, PWhT, PWlT, OUT_CH, OUT_CH, (b - PW1B) * 2048 + tid * 8);
    }
}

// =====================================================================
// GEMM0: C = x @ W0.  64x128 tile (grid 2x782 = 1564 blocks = 6.1/CU --
// the R8 kernel was GRID-STARVED at 782 blocks = 3.05/CU, occupancy 21%).
// Single-buffer 24KB LDS, reg-staged A (8 fp32/thread) loaded one K-step
// AHEAD (counted vmcnt keeps the prefetch in flight across the barrier),
// truncation-split ONCE into bf16 h/l LDS planes (swizzled ds_write).
// B via global_load_lds from pre-swizzled storage.
// Epilogue scales by rsqrt(cnt+1) (fused dinv).
// =====================================================================
__global__ __launch_bounds__(256, 3) void gemm0_x(const float* __restrict__ A,
                                                  const ushort_t* __restrict__ BhT,
                                                  const ushort_t* __restrict__ BlT,
                                                  const int* __restrict__ cnt,
                                                  _Float16* __restrict__ C,
                                                  int M, int N) {
    constexpr int KT = IN_CH;
    constexpr int NT = KT / 32;                    // 16
    __shared__ ushort_t smA[2][64 * 32];           // h/l planes, 8 KB
    __shared__ ushort_t smB[2][128 * 32];          // Bh/Bl, 16 KB
    const int tid  = threadIdx.x;
    const int wave = tid >> 6, lane = tid & 63;
    const int m0 = blockIdx.y * 64, n0 = blockIdx.x * 128;

    // --- A staging map: thread -> (row sr, 8-float segment sseg) ---
    const int sr = tid >> 2, sseg = tid & 3;
    const float* gA = A + (size_t)min(m0 + sr, M - 1) * KT + sseg * 8;
    const int wo = sr * 32 + ((sseg ^ ((sr >> 1) & 3)) * 8);

    // --- B staging via global_load_lds (storage pre-swizzled in k_prep) ---
    const int c0 = wave * 128 + lane, c1 = c0 + 64;
    const ushort_t* gbh0 = BhT + (size_t)(n0 + (c0 >> 2)) * KT + (c0 & 3) * 8;
    const ushort_t* gbh1 = BhT + (size_t)(n0 + (c1 >> 2)) * KT + (c1 & 3) * 8;
    const ushort_t* gbl0 = BlT + (size_t)(n0 + (c0 >> 2)) * KT + (c0 & 3) * 8;
    const ushort_t* gbl1 = BlT + (size_t)(n0 + (c1 >> 2)) * KT + (c1 & 3) * 8;
    ushort_t* lb0 = &smB[0][wave * 1024];  ushort_t* lb1 = &smB[0][wave * 1024 + 512];
    ushort_t* lc0 = &smB[1][wave * 1024];  ushort_t* lc1 = &smB[1][wave * 1024 + 512];

    float4 q0, q1;                                 // A regs (one K-step ahead)
    auto loadA = [&]() {
        q0 = ((const float4*)gA)[0]; q1 = ((const float4*)gA)[1];
        gA += 32;
    };
    auto writeA = [&]() {                          // truncation split + dword pack, ONCE
        float vv[8] = {q0.x, q0.y, q0.z, q0.w, q1.x, q1.y, q1.z, q1.w};
        unsigned hp[4], lp[4];
        #pragma unroll
        for (int j = 0; j < 4; ++j) {
            unsigned ua = __float_as_uint(vv[2 * j]);
            unsigned ub = __float_as_uint(vv[2 * j + 1]);
            unsigned ha = ua & 0xffff0000u, hb = ub & 0xffff0000u;
            hp[j] = (ua >> 16) | hb;
            float ra = vv[2 * j]     - __uint_as_float(ha);
            float rb = vv[2 * j + 1] - __uint_as_float(hb);
            lp[j] = (__float_as_uint(ra) >> 16) | (__float_as_uint(rb) & 0xffff0000u);
        }
        *(uint4*)&smA[0][wo] = make_uint4(hp[0], hp[1], hp[2], hp[3]);
        *(uint4*)&smA[1][wo] = make_uint4(lp[0], lp[1], lp[2], lp[3]);
    };

    floatx4 zero = {0.f, 0.f, 0.f, 0.f};
    floatx4 acc[2][4];
    #pragma unroll
    for (int i = 0; i < 2; ++i)
        #pragma unroll
        for (int j = 0; j < 4; ++j) acc[i][j] = zero;

    const int wm = (wave & 1) * 32, wn = (wave >> 1) * 64;
    const int fr = lane & 15, fq = lane >> 4;
    const int sx = SWZ(fr);

    loadA();                                       // A(0) in regs
    for (int t = 0; t < NT; ++t) {
        // issue B(t) first so vmcnt(2) below = "B(t) done, A(t+1) in flight"
        gl_lds16(gbh0, lb0); gl_lds16(gbh1, lb1);
        gl_lds16(gbl0, lc0); gl_lds16(gbl1, lc1);
        gbh0 += 32; gbh1 += 32; gbl0 += 32; gbl1 += 32;
        writeA();                                  // waits A(t) regs, split, ds_write
        __builtin_amdgcn_sched_barrier(0);         // pin: B issue + writeA before loadA
        if (t + 1 < NT) {
            loadA();                               // A(t+1) issue (prefetch, 2 loads)
            __builtin_amdgcn_sched_barrier(0);
            asm volatile("s_waitcnt vmcnt(2) lgkmcnt(0)" ::: "memory");
        } else {
            asm volatile("s_waitcnt vmcnt(0) lgkmcnt(0)" ::: "memory");
        }
        __builtin_amdgcn_sched_barrier(0);
        __builtin_amdgcn_s_barrier();
        __builtin_amdgcn_sched_barrier(0);

        short8 afh[2], afl[2], bfh[4], bfl[4];
        #pragma unroll
        for (int tt = 0; tt < 2; ++tt) {
            int ai = (wm + tt * 16 + fr) * 32 + (fq * 8 ^ sx);
            afh[tt] = *(const short8*)&smA[0][ai];
            afl[tt] = *(const short8*)&smA[1][ai];
        }
        #pragma unroll
        for (int tt = 0; tt < 4; ++tt) {
            int bi = (wn + tt * 16 + fr) * 32 + (fq * 8 ^ sx);
            bfh[tt] = *(const short8*)&smB[0][bi];
            bfl[tt] = *(const short8*)&smB[1][bi];
        }
        #pragma unroll
        for (int i = 0; i < 2; ++i)
            #pragma unroll
            for (int j = 0; j < 4; ++j) {
                acc[i][j] = __builtin_amdgcn_mfma_f32_16x16x32_bf16(afh[i], bfh[j], acc[i][j], 0, 0, 0);
                acc[i][j] = __builtin_amdgcn_mfma_f32_16x16x32_bf16(afh[i], bfl[j], acc[i][j], 0, 0, 0);
                acc[i][j] = __builtin_amdgcn_mfma_f32_16x16x32_bf16(afl[i], bfh[j], acc[i][j], 0, 0, 0);
            }
        __builtin_amdgcn_sched_barrier(0);
        __builtin_amdgcn_s_barrier();              // LDS safe for next step's writes
        __builtin_amdgcn_sched_barrier(0);
    }
    const int colb = n0 + wn + fr;
    #pragma unroll
    for (int i = 0; i < 2; ++i) {
        int rowb = m0 + wm + i * 16 + fq * 4;
        #pragma unroll
        for (int r = 0; r < 4; ++r) {
            int row = rowb + r;
            if (row < M) {
                float dv = rsqrtf((float)cnt[row] + 1.0f);   // fused dinv
                _Float16* cp = C + (size_t)row * N + colb;
                cp[0]  = (_Float16)(acc[i][0][r] * dv);
                cp[16] = (_Float16)(acc[i][1][r] * dv);
                cp[32] = (_Float16)(acc[i][2][r] * dv);
                cp[48] = (_Float16)(acc[i][3][r] * dv);
            }
        }
    }
}

// =====================================================================
// GEMM1 (split-bf16 A/B, all global_load_lds), 64x128 tile (grid 782 vs
// R8's 391 = 1.5 blocks/CU), single-buffer 24KB, 2-barrier loop.
// Epilogue scales by rsqrt(cnt+1) (fused dinv).
// =====================================================================
template <int KT>
__global__ __launch_bounds__(256, 3) void gemm_bf(const ushort_t* __restrict__ Ah,
                                                  const ushort_t* __restrict__ Al,
                                                  const ushort_t* __restrict__ BhT,
                                                  const ushort_t* __restrict__ BlT,
                                                  const int* __restrict__ cnt,
                                                  _Float16* __restrict__ C,
                                                  int M, int N) {
    constexpr int NT = KT / 32;
    __shared__ ushort_t smA[2][64 * 32];           // 8 KB
    __shared__ ushort_t smB[2][128 * 32];          // 16 KB
    const int tid  = threadIdx.x;
    const int wave = tid >> 6, lane = tid & 63;
    const int m0 = blockIdx.y * 64, n0 = blockIdx.x * 128;

    // A: 64 rows x 4 chunks = 256 threads -> 1 gl_lds per plane
    const int ar = min(m0 + (tid >> 2), M - 1);
    const ushort_t* gah = Ah + (size_t)ar * KT + (tid & 3) * 8;
    const ushort_t* gal = Al + (size_t)ar * KT + (tid & 3) * 8;
    const int c0 = wave * 128 + lane, c1 = c0 + 64;
    const ushort_t* gbh0 = BhT + (size_t)(n0 + (c0 >> 2)) * KT + (c0 & 3) * 8;
    const ushort_t* gbh1 = BhT + (size_t)(n0 + (c1 >> 2)) * KT + (c1 & 3) * 8;
    const ushort_t* gbl0 = BlT + (size_t)(n0 + (c0 >> 2)) * KT + (c0 & 3) * 8;
    const ushort_t* gbl1 = BlT + (size_t)(n0 + (c1 >> 2)) * KT + (c1 & 3) * 8;
    ushort_t* laH = &smA[0][wave * 512];
    ushort_t* laL = &smA[1][wave * 512];
    ushort_t* lb0 = &smB[0][wave * 1024];  ushort_t* lb1 = &smB[0][wave * 1024 + 512];
    ushort_t* lc0 = &smB[1][wave * 1024];  ushort_t* lc1 = &smB[1][wave * 1024 + 512];

    floatx4 zero = {0.f, 0.f, 0.f, 0.f};
    floatx4 acc[2][4];
    #pragma unroll
    for (int i = 0; i < 2; ++i)
        #pragma unroll
        for (int j = 0; j < 4; ++j) acc[i][j] = zero;

    const int wm = (wave & 1) * 32, wn = (wave >> 1) * 64;
    const int fr = lane & 15, fq = lane >> 4;
    const int sx = SWZ(fr);

    for (int t = 0; t < NT; ++t) {
        gl_lds16(gah, laH); gl_lds16(gal, laL);
        gl_lds16(gbh0, lb0); gl_lds16(gbh1, lb1);
        gl_lds16(gbl0, lc0); gl_lds16(gbl1, lc1);
        gah += 32; gal += 32;
        gbh0 += 32; gbh1 += 32; gbl0 += 32; gbl1 += 32;
        __syncthreads();
        short8 afh[2], afl[2], bfh[4], bfl[4];
        #pragma unroll
        for (int tt = 0; tt < 2; ++tt) {
            int ai = (wm + tt * 16 + fr) * 32 + (fq * 8 ^ sx);
            afh[tt] = *(const short8*)&smA[0][ai];
            afl[tt] = *(const short8*)&smA[1][ai];
        }
        #pragma unroll
        for (int tt = 0; tt < 4; ++tt) {
            int bi = (wn + tt * 16 + fr) * 32 + (fq * 8 ^ sx);
            bfh[tt] = *(const short8*)&smB[0][bi];
            bfl[tt] = *(const short8*)&smB[1][bi];
        }
        #pragma unroll
        for (int i = 0; i < 2; ++i)
            #pragma unroll
            for (int j = 0; j < 4; ++j) {
                acc[i][j] = __builtin_amdgcn_mfma_f32_16x16x32_bf16(afh[i], bfh[j], acc[i][j], 0, 0, 0);
                acc[i][j] = __builtin_amdgcn_mfma_f32_16x16x32_bf16(afh[i], bfl[j], acc[i][j], 0, 0, 0);
                acc[i][j] = __builtin_amdgcn_mfma_f32_16x16x32_bf16(afl[i], bfh[j], acc[i][j], 0, 0, 0);
            }
        __syncthreads();
    }
    const int colb = n0 + wn + fr;
    #pragma unroll
    for (int i = 0; i < 2; ++i) {
        int rowb = m0 + wm + i * 16 + fq * 4;
        #pragma unroll
        for (int r = 0; r < 4; ++r) {
            int row = rowb + r;
            if (row < M) {
                float dv = rsqrtf((float)cnt[row] + 1.0f);
                _Float16* cp = C + (size_t)row * N + colb;
                cp[0]  = (_Float16)(acc[i][0][r] * dv);
                cp[16] = (_Float16)(acc[i][1][r] * dv);
                cp[32] = (_Float16)(acc[i][2][r] * dv);
                cp[48] = (_Float16)(acc[i][3][r] * dv);
            }
        }
    }
}

// =====================================================================
// PGE GEMM: p-strip = h1 @ PW, 64x128 tile (grid 782), FUSED col max/argmax.
// =====================================================================
__global__ __launch_bounds__(256, 3) void gemm_pge(const ushort_t* __restrict__ Ah,
                                                   const ushort_t* __restrict__ Al,
                                                   const ushort_t* __restrict__ BhT,
                                                   const ushort_t* __restrict__ BlT,
                                                   float* __restrict__ pv,
                                                   int* __restrict__ pi,
                                                   int M) {
    constexpr int KT = OUT_CH;                     // 128
    constexpr int NT = KT / 32;                    // 4
    __shared__ ushort_t smA[2][64 * 32];
    __shared__ ushort_t smB[2][128 * 32];
    __shared__ float redv[8][128];
    __shared__ int   redi[8][128];
    const int tid  = threadIdx.x;
    const int wave = tid >> 6, lane = tid & 63;
    const int m0 = blockIdx.x * 64;

    const int ar = min(m0 + (tid >> 2), M - 1);
    const ushort_t* gah = Ah + (size_t)ar * KT + (tid & 3) * 8;
    const ushort_t* gal = Al + (size_t)ar * KT + (tid & 3) * 8;
    const int c0 = wave * 128 + lane, c1 = c0 + 64;
    const ushort_t* gbh0 = BhT + (size_t)(c0 >> 2) * KT + (c0 & 3) * 8;
    const ushort_t* gbh1 = BhT + (size_t)(c1 >> 2) * KT + (c1 & 3) * 8;
    const ushort_t* gbl0 = BlT + (size_t)(c0 >> 2) * KT + (c0 & 3) * 8;
    const ushort_t* gbl1 = BlT + (size_t)(c1 >> 2) * KT + (c1 & 3) * 8;
    ushort_t* laH = &smA[0][wave * 512];
    ushort_t* laL = &smA[1][wave * 512];
    ushort_t* lb0 = &smB[0][wave * 1024];  ushort_t* lb1 = &smB[0][wave * 1024 + 512];
    ushort_t* lc0 = &smB[1][wave * 1024];  ushort_t* lc1 = &smB[1][wave * 1024 + 512];

    floatx4 zero = {0.f, 0.f, 0.f, 0.f};
    floatx4 acc[2][4];
    #pragma unroll
    for (int i = 0; i < 2; ++i)
        #pragma unroll
        for (int j = 0; j < 4; ++j) acc[i][j] = zero;

    const int wm = (wave & 1) * 32, wn = (wave >> 1) * 64;
    const int fr = lane & 15, fq = lane >> 4;
    const int sx = SWZ(fr);

    for (int t = 0; t < NT; ++t) {
        gl_lds16(gah, laH); gl_lds16(gal, laL);
        gl_lds16(gbh0, lb0); gl_lds16(gbh1, lb1);
        gl_lds16(gbl0, lc0); gl_lds16(gbl1, lc1);
        gah += 32; gal += 32;
        gbh0 += 32; gbh1 += 32; gbl0 += 32; gbl1 += 32;
        __syncthreads();
        short8 afh[2], afl[2], bfh[4], bfl[4];
        #pragma unroll
        for (int tt = 0; tt < 2; ++tt) {
            int ai = (wm + tt * 16 + fr) * 32 + (fq * 8 ^ sx);
            afh[tt] = *(const short8*)&smA[0][ai];
            afl[tt] = *(const short8*)&smA[1][ai];
        }
        #pragma unroll
        for (int tt = 0; tt < 4; ++tt) {
            int bi = (wn + tt * 16 + fr) * 32 + (fq * 8 ^ sx);
            bfh[tt] = *(const short8*)&smB[0][bi];
            bfl[tt] = *(const short8*)&smB[1][bi];
        }
        #pragma unroll
        for (int i = 0; i < 2; ++i)
            #pragma unroll
            for (int j = 0; j < 4; ++j) {
                acc[i][j] = __builtin_amdgcn_mfma_f32_16x16x32_bf16(afh[i], bfh[j], acc[i][j], 0, 0, 0);
                acc[i][j] = __builtin_amdgcn_mfma_f32_16x16x32_bf16(afh[i], bfl[j], acc[i][j], 0, 0, 0);
                acc[i][j] = __builtin_amdgcn_mfma_f32_16x16x32_bf16(afl[i], bfh[j], acc[i][j], 0, 0, 0);
            }
        __syncthreads();
    }
    // ---- fused epilogue: column max/argmax over this 64-row strip ----
    const int slot = (wave & 1) * 4 + fq;
    #pragma unroll
    for (int j = 0; j < 4; ++j) {
        float bv = -3.402823466e+38f; int bidx = 0;
        #pragma unroll
        for (int i = 0; i < 2; ++i) {
            int rowb = m0 + wm + i * 16 + fq * 4;
            #pragma unroll
            for (int r = 0; r < 4; ++r) {
                int row = rowb + r;
                float v = acc[i][j][r];
                if (row < M && v > bv) { bv = v; bidx = row; }   // strict > keeps lowest row
            }
        }
        redv[slot][wn + j * 16 + fr] = bv;
        redi[slot][wn + j * 16 + fr] = bidx;
    }
    __syncthreads();
    if (tid < 128) {
        float bv = redv[0][tid]; int bidx = redi[0][tid];
        #pragma unroll
        for (int s = 1; s < 8; ++s) {
            float v = redv[s][tid]; int ix = redi[s][tid];
            if (v > bv || (v == bv && ix < bidx)) { bv = v; bidx = ix; }
        }
        pv[blockIdx.x * 128 + tid] = bv;
        pi[blockIdx.x * 128 + tid] = bidx;
    }
}

// ---------------- aggregation (bucket gather, PRESCALED fp16 table) --------------------
// PROVEN geometry (R0/R8): 256-thread blocks, 4 dst/block, 8-wide batches
// (s[8]+u[8] ~ 24 VGPR fits default budget -> full MLP).  Dead lanes gather a
// memset-ZEROED dud row: exact +0.0, no mask mults, no serial tail.
__global__ __launch_bounds__(256) void agg256_relu_bf(const _Float16* __restrict__ hl,
                                                      const int* __restrict__ cnt,
                                                      const int* __restrict__ slots,
                                                      const float* __restrict__ bias,
                                                      ushort_t* __restrict__ oh,
                                                      ushort_t* __restrict__ ol) {
    int d = blockIdx.x * 4 + (threadIdx.x >> 6);
    int lane = threadIdx.x & 63;
    int n = cnt[d];
    float di = rsqrtf((float)n + 1.0f);            // fused dinv
    half4v v = ((const half4v*)(hl + (size_t)d * 256))[lane];
    float ax = (float)v[0], ay = (float)v[1], az = (float)v[2], aw = (float)v[3];
    const int* sl = slots + (size_t)d * SLOT;
    for (int e = 0; e < n; e += 8) {
        int s[8]; half4v u[8];
        #pragma unroll
        for (int j = 0; j < 8; ++j) s[j] = (e + j) < n ? sl[e + j] : DUD256;
        #pragma unroll
        for (int j = 0; j < 8; ++j) u[j] = ((const half4v*)(hl + (size_t)s[j] * 256))[lane];
        #pragma unroll
        for (int j = 0; j < 8; ++j) {
            ax += (float)u[j][0]; ay += (float)u[j][1];
            az += (float)u[j][2]; aw += (float)u[j][3];
        }
    }
    float4 b = ((const float4*)bias)[lane];
    float rx = fmaxf(fmaf(di, ax, b.x), 0.0f), ry = fmaxf(fmaf(di, ay, b.y), 0.0f);
    float rz = fmaxf(fmaf(di, az, b.z), 0.0f), rw = fmaxf(fmaf(di, aw, b.w), 0.0f);
    ushort4 hv, lv;
    hv.x = f2bf(rx); lv.x = f2bf(rx - bf2f(hv.x));
    hv.y = f2bf(ry); lv.y = f2bf(ry - bf2f(hv.y));
    hv.z = f2bf(rz); lv.z = f2bf(rz - bf2f(hv.z));
    hv.w = f2bf(rw); lv.w = f2bf(rw - bf2f(hv.w));
    int sidx = (lane * 4) ^ SWZ(d);                // pre-swizzled split storage
    *(ushort4*)&oh[(size_t)d * 256 + sidx] = hv;
    *(ushort4*)&ol[(size_t)d * 256 + sidx] = lv;
}

__global__ __launch_bounds__(256) void agg128_bias_bf(const _Float16* __restrict__ hl,
                                                      const int* __restrict__ cnt,
                                                      const int* __restrict__ slots,
                                                      const float* __restrict__ bias,
                                                      float* __restrict__ out,
                                                      ushort_t* __restrict__ oh,
                                                      ushort_t* __restrict__ ol) {
    int d = blockIdx.x * 4 + (threadIdx.x >> 6);
    int lane = threadIdx.x & 63;
    int n = cnt[d];
    float di = rsqrtf((float)n + 1.0f);            // fused dinv
    half2v v = ((const half2v*)(hl + (size_t)d * 128))[lane];
    float ax = (float)v[0], ay = (float)v[1];
    const int* sl = slots + (size_t)d * SLOT;
    for (int e = 0; e < n; e += 8) {
        int s[8]; half2v u[8];
        #pragma unroll
        for (int j = 0; j < 8; ++j) s[j] = (e + j) < n ? sl[e + j] : DUD128;
        #pragma unroll
        for (int j = 0; j < 8; ++j) u[j] = ((const half2v*)(hl + (size_t)s[j] * 128))[lane];
        #pragma unroll
        for (int j = 0; j < 8; ++j) { ax += (float)u[j][0]; ay += (float)u[j][1]; }
    }
    float2 b = ((const float2*)bias)[lane];
    float rx = fmaf(di, ax, b.x), ry = fmaf(di, ay, b.y);  // no relu (last conv layer)
    ((float2*)(out + (size_t)d * 128))[lane] = make_float2(rx, ry);
    ushort2 hv, lv;
    hv.x = f2bf(rx); lv.x = f2bf(rx - bf2f(hv.x));
    hv.y = f2bf(ry); lv.y = f2bf(ry - bf2f(hv.y));
    int sidx = (lane * 2) ^ SWZ(d);                // pre-swizzled split storage
    *(ushort2*)&oh[(size_t)d * 128 + sidx] = hv;
    *(ushort2*)&ol[(size_t)d * 128 + sidx] = lv;
}

// ---------------- final reduce over NB3 per-strip partials ----------------
__global__ __launch_bounds__(256) void k_reduce2(const float* __restrict__ pv,
                                                 const int* __restrict__ pi,
                                                 const float* __restrict__ Pb,
                                                 float* __restrict__ out) {
    int c = threadIdx.x & 127, sub = threadIdx.x >> 7;
    float best = -3.402823466e+38f;
    int bi = 0;
    for (int b = sub; b < NB3; b += 2) {
        float v = pv[b * 128 + c];
        int ix = pi[b * 128 + c];
        if (v > best || (v == best && ix < bi)) { best = v; bi = ix; }
    }
    __shared__ float sv[128];
    __shared__ int   si[128];
    if (sub == 1) { sv[c] = best; si[c] = bi; }
    __syncthreads();
    if (sub == 0) {
        float v1 = sv[c]; int i1 = si[c];
        if (v1 > best || (v1 == best && i1 < bi)) { best = v1; bi = i1; }
        out[(size_t)N_NODES * OUT_CH + c]       = best + Pb[c];
        out[(size_t)N_NODES * OUT_CH + 128 + c] = (float)bi;
    }
}

extern "C" void kernel_launch(void* const* d_in, const int* in_sizes, int n_in,
                              void* d_out, int out_size, void* d_ws, size_t ws_size,
                              hipStream_t stream) {
    const float* x  = (const float*)d_in[0];
    const int*   ei = (const int*)d_in[1];
    const float* W0 = (const float*)d_in[2];
    const float* b0 = (const float*)d_in[3];
    const float* W1 = (const float*)d_in[4];
    const float* b1 = (const float*)d_in[5];
    const float* PW = (const float*)d_in[6];
    const float* Pb = (const float*)d_in[7];
    float* out = (float*)d_out;
    const int* esrc = ei;
    const int* edst = ei + N_EDGES;

    char* w = (char*)d_ws;
    size_t off = 0;
    auto alloc = [&](size_t bytes) -> void* {
        void* p = (void*)(w + off);
        off = (off + bytes + 255) & ~(size_t)255;
        return p;
    };
    int*       cnt    = (int*)alloc((size_t)N_NODES * 4);
    int*       slots  = (int*)alloc((size_t)N_NODES * SLOT * 4);
    float*     pmax_v = (float*)alloc((size_t)NB3 * 128 * 4);
    int*       pmax_i = (int*)alloc((size_t)NB3 * 128 * 4);
    _Float16*  bufH   = (_Float16*)alloc((size_t)NPAD * 256 * 2);        // fp16 gather table
    ushort_t*  h0h    = (ushort_t*)alloc((size_t)N_NODES * HID_CH * 2);  // swizzled split
    ushort_t*  h0l    = (ushort_t*)alloc((size_t)N_NODES * HID_CH * 2);
    ushort_t*  h1h    = (ushort_t*)alloc((size_t)N_NODES * OUT_CH * 2);
    ushort_t*  h1l    = (ushort_t*)alloc((size_t)N_NODES * OUT_CH * 2);
    ushort_t*  W0hT   = (ushort_t*)alloc((size_t)IN_CH * HID_CH * 2);
    ushort_t*  W0lT   = (ushort_t*)alloc((size_t)IN_CH * HID_CH * 2);
    ushort_t*  W1hT   = (ushort_t*)alloc((size_t)HID_CH * OUT_CH * 2);
    ushort_t*  W1lT   = (ushort_t*)alloc((size_t)HID_CH * OUT_CH * 2);
    ushort_t*  PWhT   = (ushort_t*)alloc((size_t)OUT_CH * OUT_CH * 2);
    ushort_t*  PWlT   = (ushort_t*)alloc((size_t)OUT_CH * OUT_CH * 2);

    // --- zero cnt + the dud gather rows (bufH rows >= N_NODES), capture-legal ---
    hipMemsetAsync(cnt, 0, (size_t)N_NODES * 4, stream);
    hipMemsetAsync((char*)bufH + (size_t)N_NODES * 512,
                   0, (size_t)(NPAD - N_NODES) * 512, stream);
    k_prep<<<PPWB, 256, 0, stream>>>(esrc, edst, W0, W1, PW, cnt, slots,
                                     W0hT, W0lT, W1hT, W1lT, PWhT, PWlT);

    // --- layer 0: table = dinv .* (x @ W0) ; h0 = relu(di*sum + b0) ---
    gemm0_x<<<dim3(HID_CH / 128, NB3), 256, 0, stream>>>(
        x, W0hT, W0lT, cnt, bufH, N_NODES, HID_CH);
    agg256_relu_bf<<<N_NODES / 4, 256, 0, stream>>>(bufH, cnt, slots, b0, h0h, h0l);

    // --- layer 1: table = dinv .* (h0 @ W1) ; h1 = di*sum + b1 -> d_out + split ---
    gemm_bf<HID_CH><<<dim3(1, NB3), 256, 0, stream>>>(
        h0h, h0l, W1hT, W1lT, cnt, bufH, N_NODES, OUT_CH);
    agg128_bias_bf<<<N_NODES / 4, 256, 0, stream>>>(bufH, cnt, slots, b1,
                                                    out, h1h, h1l);

    // --- PGE: fused p = h1 @ PW with per-strip max/argmax; final reduce ---
    gemm_pge<<<NB3, 256, 0, stream>>>(h1h, h1l, PWhT, PWlT, pmax_v, pmax_i, N_NODES);
    k_reduce2<<<1, 256, 0, stream>>>(pmax_v, pmax_i, Pb, out);

    (void)in_sizes; (void)n_in; (void)out_size; (void)ws_size;
}

// Round 10
// 410.998 us; speedup vs baseline: 1.3127x; 1.3127x over previous
//
#include <hip/hip_runtime.h>
#include <stdint.h>

#define N_NODES 50000
#define N_EDGES 800000
#define IN_CH   512
#define HID_CH  256
#define OUT_CH  128
#define NPAD    50048
#define SLOT    96      // padded CSR slots/node; P(Poisson(16) > 96) ~ 0

#define NB_E   3125     // ceil(800000/256)
#define NB3    782      // 64-row GEMM tiles = partial max strips (50048/64)

// zero "dud" gather rows (memset once): bufH bytes [N_NODES*512, NPAD*512)
#define DUD256 50000    // L0 table: row stride 512B -> byte 25,600,000 (zeroed)
#define DUD128 100000   // L1 table: row stride 256B -> byte 25,600,000 (zeroed)

// k_prep block ranges: bucket scatter + weight split/transpose fused
#define PBKT  NB_E          // 3125 bucket blocks (256 edges each)
#define PW0B  (PBKT + 64)   // W0 split+T: 131072/2048
#define PW1B  (PW0B + 16)   // W1 split+T: 32768/2048
#define PPWB  (PW1B + 8)    // PW split+T: 16384/2048

typedef unsigned short ushort_t;
typedef __attribute__((ext_vector_type(8))) short    short8;  // 8 bf16 (MFMA A/B frag)
typedef __attribute__((ext_vector_type(4))) float    floatx4; // MFMA C/D frag
typedef __attribute__((ext_vector_type(4))) _Float16 half4v;  // 8B gather chunk
typedef __attribute__((ext_vector_type(2))) _Float16 half2v;  // 4B gather chunk

__device__ inline ushort_t f2bf(float x) {                  // fp32 -> bf16 RNE
    union { float f; unsigned u; } v; v.f = x;
    unsigned r = v.u + 0x7fffu + ((v.u >> 16) & 1u);
    return (ushort_t)(r >> 16);
}
__device__ inline float bf2f(ushort_t h) {
    union { unsigned u; float f; } v; v.u = ((unsigned)h) << 16;
    return v.f;
}
__device__ inline void gl_lds16(const void* g, void* l) {   // async global->LDS, 16B/lane
    __builtin_amdgcn_global_load_lds((const __attribute__((address_space(1))) void*)g,
                                     (__attribute__((address_space(3))) void*)l, 16, 0, 0);
}

// LDS bank swizzle: XOR on the 16B-chunk index within each 64B k-row by
// (row>>1)&3.  All producers of split-bf16 GEMM operands store through the
// SAME swizzle so global_load_lds (linear dest) lands already-swizzled tiles.
#define SWZ(r) ((((r) >> 1) & 3) << 3)

// ---------------- fused prep: bucket scatter + weight split+transpose (swizzled) --------
__device__ inline void conv_splitT8(const float* __restrict__ W,
                                    ushort_t* __restrict__ WhT,
                                    ushort_t* __restrict__ WlT,
                                    int K, int N, int base) {
    float4 v0 = *(const float4*)(W + base);
    float4 v1 = *(const float4*)(W + base + 4);
    float vv[8] = {v0.x, v0.y, v0.z, v0.w, v1.x, v1.y, v1.z, v1.w};
    #pragma unroll
    for (int j = 0; j < 8; ++j) {
        int g = base + j;
        int k = g / N, n = g - k * N;
        int ks = k ^ SWZ(n);                       // swizzled storage position
        ushort_t h = f2bf(vv[j]);
        WhT[(size_t)n * K + ks] = h;
        WlT[(size_t)n * K + ks] = f2bf(vv[j] - bf2f(h));
    }
}

__global__ __launch_bounds__(256) void k_prep(const int* __restrict__ esrc,
                                              const int* __restrict__ edst,
                                              const float* __restrict__ W0,
                                              const float* __restrict__ W1,
                                              const float* __restrict__ PW,
                                              int* __restrict__ cnt,
                                              int* __restrict__ slots,
                                              ushort_t* W0hT, ushort_t* W0lT,
                                              ushort_t* W1hT, ushort_t* W1lT,
                                              ushort_t* PWhT, ushort_t* PWlT) {
    int b = blockIdx.x, tid = threadIdx.x;
    if (b < PBKT) {                                // padded-bucket CSR scatter
        int e = b * 256 + tid;
        if (e < N_EDGES) {
            int d = edst[e];
            int c = atomicAdd(&cnt[d], 1);
            slots[(size_t)d * SLOT + c] = esrc[e];
        }
    } else if (b < PW0B) {
        conv_splitT8(W0, W0hT, W0lT, IN_CH, HID_CH, (b - PBKT) * 2048 + tid * 8);
    } else if (b < PW1B) {
        conv_splitT8(W1, W1hT, W1lT, HID_CH, OUT_CH, (b - PW0B) * 2048 + tid * 8);
    } else {
        conv_splitT8(PW, PWhT, PWlT, OUT_CH, OUT_CH, (b - PW1B) * 2048 + tid * 8);
    }
}

// =====================================================================
// GEMM0: C = x @ W0.  64x128 tile (grid 2x782 = 1564 blocks = 6.1/CU).
// Single-buffer 24KB LDS, reg-staged A (8 fp32/thread) loaded one K-step
// AHEAD (counted vmcnt keeps the prefetch in flight across the barrier),
// truncation-split ONCE into bf16 h/l LDS planes (swizzled ds_write).
// B via global_load_lds from pre-swizzled storage.
// Epilogue scales by rsqrt(cnt+1) (fused dinv).
// =====================================================================
__global__ __launch_bounds__(256, 3) void gemm0_x(const float* __restrict__ A,
                                                  const ushort_t* __restrict__ BhT,
                                                  const ushort_t* __restrict__ BlT,
                                                  const int* __restrict__ cnt,
                                                  _Float16* __restrict__ C,
                                                  int M, int N) {
    constexpr int KT = IN_CH;
    constexpr int NT = KT / 32;                    // 16
    __shared__ ushort_t smA[2][64 * 32];           // h/l planes, 8 KB
    __shared__ ushort_t smB[2][128 * 32];          // Bh/Bl, 16 KB
    const int tid  = threadIdx.x;
    const int wave = tid >> 6, lane = tid & 63;
    const int m0 = blockIdx.y * 64, n0 = blockIdx.x * 128;

    // --- A staging map: thread -> (row sr, 8-float segment sseg) ---
    const int sr = tid >> 2, sseg = tid & 3;
    const float* gA = A + (size_t)min(m0 + sr, M - 1) * KT + sseg * 8;
    const int wo = sr * 32 + ((sseg ^ ((sr >> 1) & 3)) * 8);

    // --- B staging via global_load_lds (storage pre-swizzled in k_prep) ---
    const int c0 = wave * 128 + lane, c1 = c0 + 64;
    const ushort_t* gbh0 = BhT + (size_t)(n0 + (c0 >> 2)) * KT + (c0 & 3) * 8;
    const ushort_t* gbh1 = BhT + (size_t)(n0 + (c1 >> 2)) * KT + (c1 & 3) * 8;
    const ushort_t* gbl0 = BlT + (size_t)(n0 + (c0 >> 2)) * KT + (c0 & 3) * 8;
    const ushort_t* gbl1 = BlT + (size_t)(n0 + (c1 >> 2)) * KT + (c1 & 3) * 8;
    ushort_t* lb0 = &smB[0][wave * 1024];  ushort_t* lb1 = &smB[0][wave * 1024 + 512];
    ushort_t* lc0 = &smB[1][wave * 1024];  ushort_t* lc1 = &smB[1][wave * 1024 + 512];

    float4 q0, q1;                                 // A regs (one K-step ahead)
    auto loadA = [&]() {
        q0 = ((const float4*)gA)[0]; q1 = ((const float4*)gA)[1];
        gA += 32;
    };
    auto writeA = [&]() {                          // truncation split + dword pack, ONCE
        float vv[8] = {q0.x, q0.y, q0.z, q0.w, q1.x, q1.y, q1.z, q1.w};
        unsigned hp[4], lp[4];
        #pragma unroll
        for (int j = 0; j < 4; ++j) {
            unsigned ua = __float_as_uint(vv[2 * j]);
            unsigned ub = __float_as_uint(vv[2 * j + 1]);
            unsigned ha = ua & 0xffff0000u, hb = ub & 0xffff0000u;
            hp[j] = (ua >> 16) | hb;
            float ra = vv[2 * j]     - __uint_as_float(ha);
            float rb = vv[2 * j + 1] - __uint_as_float(hb);
            lp[j] = (__float_as_uint(ra) >> 16) | (__float_as_uint(rb) & 0xffff0000u);
        }
        *(uint4*)&smA[0][wo] = make_uint4(hp[0], hp[1], hp[2], hp[3]);
        *(uint4*)&smA[1][wo] = make_uint4(lp[0], lp[1], lp[2], lp[3]);
    };

    floatx4 zero = {0.f, 0.f, 0.f, 0.f};
    floatx4 acc[2][4];
    #pragma unroll
    for (int i = 0; i < 2; ++i)
        #pragma unroll
        for (int j = 0; j < 4; ++j) acc[i][j] = zero;

    const int wm = (wave & 1) * 32, wn = (wave >> 1) * 64;
    const int fr = lane & 15, fq = lane >> 4;
    const int sx = SWZ(fr);

    loadA();                                       // A(0) in regs
    for (int t = 0; t < NT; ++t) {
        // issue B(t) first so vmcnt(2) below = "B(t) done, A(t+1) in flight"
        gl_lds16(gbh0, lb0); gl_lds16(gbh1, lb1);
        gl_lds16(gbl0, lc0); gl_lds16(gbl1, lc1);
        gbh0 += 32; gbh1 += 32; gbl0 += 32; gbl1 += 32;
        writeA();                                  // waits A(t) regs, split, ds_write
        __builtin_amdgcn_sched_barrier(0);         // pin: B issue + writeA before loadA
        if (t + 1 < NT) {
            loadA();                               // A(t+1) issue (prefetch, 2 loads)
            __builtin_amdgcn_sched_barrier(0);
            asm volatile("s_waitcnt vmcnt(2) lgkmcnt(0)" ::: "memory");
        } else {
            asm volatile("s_waitcnt vmcnt(0) lgkmcnt(0)" ::: "memory");
        }
        __builtin_amdgcn_sched_barrier(0);
        __builtin_amdgcn_s_barrier();
        __builtin_amdgcn_sched_barrier(0);

        short8 afh[2], afl[2], bfh[4], bfl[4];
        #pragma unroll
        for (int tt = 0; tt < 2; ++tt) {
            int ai = (wm + tt * 16 + fr) * 32 + (fq * 8 ^ sx);
            afh[tt] = *(const short8*)&smA[0][ai];
            afl[tt] = *(const short8*)&smA[1][ai];
        }
        #pragma unroll
        for (int tt = 0; tt < 4; ++tt) {
            int bi = (wn + tt * 16 + fr) * 32 + (fq * 8 ^ sx);
            bfh[tt] = *(const short8*)&smB[0][bi];
            bfl[tt] = *(const short8*)&smB[1][bi];
        }
        #pragma unroll
        for (int i = 0; i < 2; ++i)
            #pragma unroll
            for (int j = 0; j < 4; ++j) {
                acc[i][j] = __builtin_amdgcn_mfma_f32_16x16x32_bf16(afh[i], bfh[j], acc[i][j], 0, 0, 0);
                acc[i][j] = __builtin_amdgcn_mfma_f32_16x16x32_bf16(afh[i], bfl[j], acc[i][j], 0, 0, 0);
                acc[i][j] = __builtin_amdgcn_mfma_f32_16x16x32_bf16(afl[i], bfh[j], acc[i][j], 0, 0, 0);
            }
        __builtin_amdgcn_sched_barrier(0);
        __builtin_amdgcn_s_barrier();              // LDS safe for next step's writes
        __builtin_amdgcn_sched_barrier(0);
    }
    const int colb = n0 + wn + fr;
    #pragma unroll
    for (int i = 0; i < 2; ++i) {
        int rowb = m0 + wm + i * 16 + fq * 4;
        #pragma unroll
        for (int r = 0; r < 4; ++r) {
            int row = rowb + r;
            if (row < M) {
                float dv = rsqrtf((float)cnt[row] + 1.0f);   // fused dinv
                _Float16* cp = C + (size_t)row * N + colb;
                cp[0]  = (_Float16)(acc[i][0][r] * dv);
                cp[16] = (_Float16)(acc[i][1][r] * dv);
                cp[32] = (_Float16)(acc[i][2][r] * dv);
                cp[48] = (_Float16)(acc[i][3][r] * dv);
            }
        }
    }
}

// =====================================================================
// GEMM1 (split-bf16 A/B, all global_load_lds), 64x128 tile (grid 782),
// single-buffer 24KB, 2-barrier loop.
// Epilogue scales by rsqrt(cnt+1) (fused dinv).
// =====================================================================
template <int KT>
__global__ __launch_bounds__(256, 3) void gemm_bf(const ushort_t* __restrict__ Ah,
                                                  const ushort_t* __restrict__ Al,
                                                  const ushort_t* __restrict__ BhT,
                                                  const ushort_t* __restrict__ BlT,
                                                  const int* __restrict__ cnt,
                                                  _Float16* __restrict__ C,
                                                  int M, int N) {
    constexpr int NT = KT / 32;
    __shared__ ushort_t smA[2][64 * 32];           // 8 KB
    __shared__ ushort_t smB[2][128 * 32];          // 16 KB
    const int tid  = threadIdx.x;
    const int wave = tid >> 6, lane = tid & 63;
    const int m0 = blockIdx.y * 64, n0 = blockIdx.x * 128;

    // A: 64 rows x 4 chunks = 256 threads -> 1 gl_lds per plane
    const int ar = min(m0 + (tid >> 2), M - 1);
    const ushort_t* gah = Ah + (size_t)ar * KT + (tid & 3) * 8;
    const ushort_t* gal = Al + (size_t)ar * KT + (tid & 3) * 8;
    const int c0 = wave * 128 + lane, c1 = c0 + 64;
    const ushort_t* gbh0 = BhT + (size_t)(n0 + (c0 >> 2)) * KT + (c0 & 3) * 8;
    const ushort_t* gbh1 = BhT + (size_t)(n0 + (c1 >> 2)) * KT + (c1 & 3) * 8;
    const ushort_t* gbl0 = BlT + (size_t)(n0 + (c0 >> 2)) * KT + (c0 & 3) * 8;
    const ushort_t* gbl1 = BlT + (size_t)(n0 + (c1 >> 2)) * KT + (c1 & 3) * 8;
    ushort_t* laH = &smA[0][wave * 512];
    ushort_t* laL = &smA[1][wave * 512];
    ushort_t* lb0 = &smB[0][wave * 1024];  ushort_t* lb1 = &smB[0][wave * 1024 + 512];
    ushort_t* lc0 = &smB[1][wave * 1024];  ushort_t* lc1 = &smB[1][wave * 1024 + 512];

    floatx4 zero = {0.f, 0.f, 0.f, 0.f};
    floatx4 acc[2][4];
    #pragma unroll
    for (int i = 0; i < 2; ++i)
        #pragma unroll
        for (int j = 0; j < 4; ++j) acc[i][j] = zero;

    const int wm = (wave & 1) * 32, wn = (wave >> 1) * 64;
    const int fr = lane & 15, fq = lane >> 4;
    const int sx = SWZ(fr);

    for (int t = 0; t < NT; ++t) {
        gl_lds16(gah, laH); gl_lds16(gal, laL);
        gl_lds16(gbh0, lb0); gl_lds16(gbh1, lb1);
        gl_lds16(gbl0, lc0); gl_lds16(gbl1, lc1);
        gah += 32; gal += 32;
        gbh0 += 32; gbh1 += 32; gbl0 += 32; gbl1 += 32;
        __syncthreads();
        short8 afh[2], afl[2], bfh[4], bfl[4];
        #pragma unroll
        for (int tt = 0; tt < 2; ++tt) {
            int ai = (wm + tt * 16 + fr) * 32 + (fq * 8 ^ sx);
            afh[tt] = *(const short8*)&smA[0][ai];
            afl[tt] = *(const short8*)&smA[1][ai];
        }
        #pragma unroll
        for (int tt = 0; tt < 4; ++tt) {
            int bi = (wn + tt * 16 + fr) * 32 + (fq * 8 ^ sx);
            bfh[tt] = *(const short8*)&smB[0][bi];
            bfl[tt] = *(const short8*)&smB[1][bi];
        }
        #pragma unroll
        for (int i = 0; i < 2; ++i)
            #pragma unroll
            for (int j = 0; j < 4; ++j) {
                acc[i][j] = __builtin_amdgcn_mfma_f32_16x16x32_bf16(afh[i], bfh[j], acc[i][j], 0, 0, 0);
                acc[i][j] = __builtin_amdgcn_mfma_f32_16x16x32_bf16(afh[i], bfl[j], acc[i][j], 0, 0, 0);
                acc[i][j] = __builtin_amdgcn_mfma_f32_16x16x32_bf16(afl[i], bfh[j], acc[i][j], 0, 0, 0);
            }
        __syncthreads();
    }
    const int colb = n0 + wn + fr;
    #pragma unroll
    for (int i = 0; i < 2; ++i) {
        int rowb = m0 + wm + i * 16 + fq * 4;
        #pragma unroll
        for (int r = 0; r < 4; ++r) {
            int row = rowb + r;
            if (row < M) {
                float dv = rsqrtf((float)cnt[row] + 1.0f);
                _Float16* cp = C + (size_t)row * N + colb;
                cp[0]  = (_Float16)(acc[i][0][r] * dv);
                cp[16] = (_Float16)(acc[i][1][r] * dv);
                cp[32] = (_Float16)(acc[i][2][r] * dv);
                cp[48] = (_Float16)(acc[i][3][r] * dv);
            }
        }
    }
}

// =====================================================================
// PGE GEMM: p-strip = h1 @ PW, 64x128 tile (grid 782), FUSED col max/argmax.
// =====================================================================
__global__ __launch_bounds__(256, 3) void gemm_pge(const ushort_t* __restrict__ Ah,
                                                   const ushort_t* __restrict__ Al,
                                                   const ushort_t* __restrict__ BhT,
                                                   const ushort_t* __restrict__ BlT,
                                                   float* __restrict__ pv,
                                                   int* __restrict__ pi,
                                                   int M) {
    constexpr int KT = OUT_CH;                     // 128
    constexpr int NT = KT / 32;                    // 4
    __shared__ ushort_t smA[2][64 * 32];
    __shared__ ushort_t smB[2][128 * 32];
    __shared__ float redv[8][128];
    __shared__ int   redi[8][128];
    const int tid  = threadIdx.x;
    const int wave = tid >> 6, lane = tid & 63;
    const int m0 = blockIdx.x * 64;

    const int ar = min(m0 + (tid >> 2), M - 1);
    const ushort_t* gah = Ah + (size_t)ar * KT + (tid & 3) * 8;
    const ushort_t* gal = Al + (size_t)ar * KT + (tid & 3) * 8;
    const int c0 = wave * 128 + lane, c1 = c0 + 64;
    const ushort_t* gbh0 = BhT + (size_t)(c0 >> 2) * KT + (c0 & 3) * 8;
    const ushort_t* gbh1 = BhT + (size_t)(c1 >> 2) * KT + (c1 & 3) * 8;
    const ushort_t* gbl0 = BlT + (size_t)(c0 >> 2) * KT + (c0 & 3) * 8;
    const ushort_t* gbl1 = BlT + (size_t)(c1 >> 2) * KT + (c1 & 3) * 8;
    ushort_t* laH = &smA[0][wave * 512];
    ushort_t* laL = &smA[1][wave * 512];
    ushort_t* lb0 = &smB[0][wave * 1024];  ushort_t* lb1 = &smB[0][wave * 1024 + 512];
    ushort_t* lc0 = &smB[1][wave * 1024];  ushort_t* lc1 = &smB[1][wave * 1024 + 512];

    floatx4 zero = {0.f, 0.f, 0.f, 0.f};
    floatx4 acc[2][4];
    #pragma unroll
    for (int i = 0; i < 2; ++i)
        #pragma unroll
        for (int j = 0; j < 4; ++j) acc[i][j] = zero;

    const int wm = (wave & 1) * 32, wn = (wave >> 1) * 64;
    const int fr = lane & 15, fq = lane >> 4;
    const int sx = SWZ(fr);

    for (int t = 0; t < NT; ++t) {
        gl_lds16(gah, laH); gl_lds16(gal, laL);
        gl_lds16(gbh0, lb0); gl_lds16(gbh1, lb1);
        gl_lds16(gbl0, lc0); gl_lds16(gbl1, lc1);
        gah += 32; gal += 32;
        gbh0 += 32; gbh1 += 32; gbl0 += 32; gbl1 += 32;
        __syncthreads();
        short8 afh[2], afl[2], bfh[4], bfl[4];
        #pragma unroll
        for (int tt = 0; tt < 2; ++tt) {
            int ai = (wm + tt * 16 + fr) * 32 + (fq * 8 ^ sx);
            afh[tt] = *(const short8*)&smA[0][ai];
            afl[tt] = *(const short8*)&smA[1][ai];
        }
        #pragma unroll
        for (int tt = 0; tt < 4; ++tt) {
            int bi = (wn + tt * 16 + fr) * 32 + (fq * 8 ^ sx);
            bfh[tt] = *(const short8*)&smB[0][bi];
            bfl[tt] = *(const short8*)&smB[1][bi];
        }
        #pragma unroll
        for (int i = 0; i < 2; ++i)
            #pragma unroll
            for (int j = 0; j < 4; ++j) {
                acc[i][j] = __builtin_amdgcn_mfma_f32_16x16x32_bf16(afh[i], bfh[j], acc[i][j], 0, 0, 0);
                acc[i][j] = __builtin_amdgcn_mfma_f32_16x16x32_bf16(afh[i], bfl[j], acc[i][j], 0, 0, 0);
                acc[i][j] = __builtin_amdgcn_mfma_f32_16x16x32_bf16(afl[i], bfh[j], acc[i][j], 0, 0, 0);
            }
        __syncthreads();
    }
    // ---- fused epilogue: column max/argmax over this 64-row strip ----
    const int slot = (wave & 1) * 4 + fq;
    #pragma unroll
    for (int j = 0; j < 4; ++j) {
        float bv = -3.402823466e+38f; int bidx = 0;
        #pragma unroll
        for (int i = 0; i < 2; ++i) {
            int rowb = m0 + wm + i * 16 + fq * 4;
            #pragma unroll
            for (int r = 0; r < 4; ++r) {
                int row = rowb + r;
                float v = acc[i][j][r];
                if (row < M && v > bv) { bv = v; bidx = row; }   // strict > keeps lowest row
            }
        }
        redv[slot][wn + j * 16 + fr] = bv;
        redi[slot][wn + j * 16 + fr] = bidx;
    }
    __syncthreads();
    if (tid < 128) {
        float bv = redv[0][tid]; int bidx = redi[0][tid];
        #pragma unroll
        for (int s = 1; s < 8; ++s) {
            float v = redv[s][tid]; int ix = redi[s][tid];
            if (v > bv || (v == bv && ix < bidx)) { bv = v; bidx = ix; }
        }
        pv[blockIdx.x * 128 + tid] = bv;
        pi[blockIdx.x * 128 + tid] = bidx;
    }
}

// ---------------- aggregation (bucket gather, PRESCALED fp16 table) --------------------
// PROVEN geometry (R0/R8): 256-thread blocks, 4 dst/block, 8-wide batches
// (s[8]+u[8] ~ 24 VGPR fits default budget -> full MLP).  Dead lanes gather a
// memset-ZEROED dud row: exact +0.0, no mask mults, no serial tail.
__global__ __launch_bounds__(256) void agg256_relu_bf(const _Float16* __restrict__ hl,
                                                      const int* __restrict__ cnt,
                                                      const int* __restrict__ slots,
                                                      const float* __restrict__ bias,
                                                      ushort_t* __restrict__ oh,
                                                      ushort_t* __restrict__ ol) {
    int d = blockIdx.x * 4 + (threadIdx.x >> 6);
    int lane = threadIdx.x & 63;
    int n = cnt[d];
    float di = rsqrtf((float)n + 1.0f);            // fused dinv
    half4v v = ((const half4v*)(hl + (size_t)d * 256))[lane];
    float ax = (float)v[0], ay = (float)v[1], az = (float)v[2], aw = (float)v[3];
    const int* sl = slots + (size_t)d * SLOT;
    for (int e = 0; e < n; e += 8) {
        int s[8]; half4v u[8];
        #pragma unroll
        for (int j = 0; j < 8; ++j) s[j] = (e + j) < n ? sl[e + j] : DUD256;
        #pragma unroll
        for (int j = 0; j < 8; ++j) u[j] = ((const half4v*)(hl + (size_t)s[j] * 256))[lane];
        #pragma unroll
        for (int j = 0; j < 8; ++j) {
            ax += (float)u[j][0]; ay += (float)u[j][1];
            az += (float)u[j][2]; aw += (float)u[j][3];
        }
    }
    float4 b = ((const float4*)bias)[lane];
    float rx = fmaxf(fmaf(di, ax, b.x), 0.0f), ry = fmaxf(fmaf(di, ay, b.y), 0.0f);
    float rz = fmaxf(fmaf(di, az, b.z), 0.0f), rw = fmaxf(fmaf(di, aw, b.w), 0.0f);
    ushort4 hv, lv;
    hv.x = f2bf(rx); lv.x = f2bf(rx - bf2f(hv.x));
    hv.y = f2bf(ry); lv.y = f2bf(ry - bf2f(hv.y));
    hv.z = f2bf(rz); lv.z = f2bf(rz - bf2f(hv.z));
    hv.w = f2bf(rw); lv.w = f2bf(rw - bf2f(hv.w));
    int sidx = (lane * 4) ^ SWZ(d);                // pre-swizzled split storage
    *(ushort4*)&oh[(size_t)d * 256 + sidx] = hv;
    *(ushort4*)&ol[(size_t)d * 256 + sidx] = lv;
}

__global__ __launch_bounds__(256) void agg128_bias_bf(const _Float16* __restrict__ hl,
                                                      const int* __restrict__ cnt,
                                                      const int* __restrict__ slots,
                                                      const float* __restrict__ bias,
                                                      float* __restrict__ out,
                                                      ushort_t* __restrict__ oh,
                                                      ushort_t* __restrict__ ol) {
    int d = blockIdx.x * 4 + (threadIdx.x >> 6);
    int lane = threadIdx.x & 63;
    int n = cnt[d];
    float di = rsqrtf((float)n + 1.0f);            // fused dinv
    half2v v = ((const half2v*)(hl + (size_t)d * 128))[lane];
    float ax = (float)v[0], ay = (float)v[1];
    const int* sl = slots + (size_t)d * SLOT;
    for (int e = 0; e < n; e += 8) {
        int s[8]; half2v u[8];
        #pragma unroll
        for (int j = 0; j < 8; ++j) s[j] = (e + j) < n ? sl[e + j] : DUD128;
        #pragma unroll
        for (int j = 0; j < 8; ++j) u[j] = ((const half2v*)(hl + (size_t)s[j] * 128))[lane];
        #pragma unroll
        for (int j = 0; j < 8; ++j) { ax += (float)u[j][0]; ay += (float)u[j][1]; }
    }
    float2 b = ((const float2*)bias)[lane];
    float rx = fmaf(di, ax, b.x), ry = fmaf(di, ay, b.y);  // no relu (last conv layer)
    ((float2*)(out + (size_t)d * 128))[lane] = make_float2(rx, ry);
    ushort2 hv, lv;
    hv.x = f2bf(rx); lv.x = f2bf(rx - bf2f(hv.x));
    hv.y = f2bf(ry); lv.y = f2bf(ry - bf2f(hv.y));
    int sidx = (lane * 2) ^ SWZ(d);                // pre-swizzled split storage
    *(ushort2*)&oh[(size_t)d * 128 + sidx] = hv;
    *(ushort2*)&ol[(size_t)d * 128 + sidx] = lv;
}

// ---------------- final reduce: ONE BLOCK PER COLUMN (was 1 block total =
// 135us latency-bound serial scan).  (max, lowest-index-on-tie) combine is
// associative -> bit-identical to the serial scan.  All data L2-resident. ----
__global__ __launch_bounds__(256) void k_reduce2(const float* __restrict__ pv,
                                                 const int* __restrict__ pi,
                                                 const float* __restrict__ Pb,
                                                 float* __restrict__ out) {
    const int c = blockIdx.x;                      // column 0..127
    const int t = threadIdx.x;
    float best = -3.402823466e+38f;
    int bi = 0;
    for (int b = t; b < NB3; b += 256) {           // ~3 strips/thread
        float v = pv[b * 128 + c];
        int ix = pi[b * 128 + c];
        if (v > best || (v == best && ix < bi)) { best = v; bi = ix; }
    }
    #pragma unroll
    for (int off = 32; off > 0; off >>= 1) {       // wave64 shuffle tree
        float v = __shfl_down(best, off);
        int ix = __shfl_down(bi, off);
        if (v > best || (v == best && ix < bi)) { best = v; bi = ix; }
    }
    __shared__ float sv[4];
    __shared__ int   si[4];
    const int wave = t >> 6, lane = t & 63;
    if (lane == 0) { sv[wave] = best; si[wave] = bi; }
    __syncthreads();
    if (t == 0) {
        #pragma unroll
        for (int wv = 1; wv < 4; ++wv) {
            if (sv[wv] > best || (sv[wv] == best && si[wv] < bi)) {
                best = sv[wv]; bi = si[wv];
            }
        }
        out[(size_t)N_NODES * OUT_CH + c]       = best + Pb[c];
        out[(size_t)N_NODES * OUT_CH + 128 + c] = (float)bi;
    }
}

extern "C" void kernel_launch(void* const* d_in, const int* in_sizes, int n_in,
                              void* d_out, int out_size, void* d_ws, size_t ws_size,
                              hipStream_t stream) {
    const float* x  = (const float*)d_in[0];
    const int*   ei = (const int*)d_in[1];
    const float* W0 = (const float*)d_in[2];
    const float* b0 = (const float*)d_in[3];
    const float* W1 = (const float*)d_in[4];
    const float* b1 = (const float*)d_in[5];
    const float* PW = (const float*)d_in[6];
    const float* Pb = (const float*)d_in[7];
    float* out = (float*)d_out;
    const int* esrc = ei;
    const int* edst = ei + N_EDGES;

    char* w = (char*)d_ws;
    size_t off = 0;
    auto alloc = [&](size_t bytes) -> void* {
        void* p = (void*)(w + off);
        off = (off + bytes + 255) & ~(size_t)255;
        return p;
    };
    int*       cnt    = (int*)alloc((size_t)N_NODES * 4);
    int*       slots  = (int*)alloc((size_t)N_NODES * SLOT * 4);
    float*     pmax_v = (float*)alloc((size_t)NB3 * 128 * 4);
    int*       pmax_i = (int*)alloc((size_t)NB3 * 128 * 4);
    _Float16*  bufH   = (_Float16*)alloc((size_t)NPAD * 256 * 2);        // fp16 gather table
    ushort_t*  h0h    = (ushort_t*)alloc((size_t)N_NODES * HID_CH * 2);  // swizzled split
    ushort_t*  h0l    = (ushort_t*)alloc((size_t)N_NODES * HID_CH * 2);
    ushort_t*  h1h    = (ushort_t*)alloc((size_t)N_NODES * OUT_CH * 2);
    ushort_t*  h1l    = (ushort_t*)alloc((size_t)N_NODES * OUT_CH * 2);
    ushort_t*  W0hT   = (ushort_t*)alloc((size_t)IN_CH * HID_CH * 2);
    ushort_t*  W0lT   = (ushort_t*)alloc((size_t)IN_CH * HID_CH * 2);
    ushort_t*  W1hT   = (ushort_t*)alloc((size_t)HID_CH * OUT_CH * 2);
    ushort_t*  W1lT   = (ushort_t*)alloc((size_t)HID_CH * OUT_CH * 2);
    ushort_t*  PWhT   = (ushort_t*)alloc((size_t)OUT_CH * OUT_CH * 2);
    ushort_t*  PWlT   = (ushort_t*)alloc((size_t)OUT_CH * OUT_CH * 2);

    // --- zero cnt + the dud gather rows (bufH rows >= N_NODES), capture-legal ---
    hipMemsetAsync(cnt, 0, (size_t)N_NODES * 4, stream);
    hipMemsetAsync((char*)bufH + (size_t)N_NODES * 512,
                   0, (size_t)(NPAD - N_NODES) * 512, stream);
    k_prep<<<PPWB, 256, 0, stream>>>(esrc, edst, W0, W1, PW, cnt, slots,
                                     W0hT, W0lT, W1hT, W1lT, PWhT, PWlT);

    // --- layer 0: table = dinv .* (x @ W0) ; h0 = relu(di*sum + b0) ---
    gemm0_x<<<dim3(HID_CH / 128, NB3), 256, 0, stream>>>(
        x, W0hT, W0lT, cnt, bufH, N_NODES, HID_CH);
    agg256_relu_bf<<<N_NODES / 4, 256, 0, stream>>>(bufH, cnt, slots, b0, h0h, h0l);

    // --- layer 1: table = dinv .* (h0 @ W1) ; h1 = di*sum + b1 -> d_out + split ---
    gemm_bf<HID_CH><<<dim3(1, NB3), 256, 0, stream>>>(
        h0h, h0l, W1hT, W1lT, cnt, bufH, N_NODES, OUT_CH);
    agg128_bias_bf<<<N_NODES / 4, 256, 0, stream>>>(bufH, cnt, slots, b1,
                                                    out, h1h, h1l);

    // --- PGE: fused p = h1 @ PW with per-strip max/argmax; parallel final reduce ---
    gemm_pge<<<NB3, 256, 0, stream>>>(h1h, h1l, PWhT, PWlT, pmax_v, pmax_i, N_NODES);
    k_reduce2<<<128, 256, 0, stream>>>(pmax_v, pmax_i, Pb, out);

    (void)in_sizes; (void)n_in; (void)out_size; (void)ws_size;
}